// Round 1
// baseline (816.427 us; speedup 1.0000x reference)
//
#include <hip/hip_runtime.h>

typedef __attribute__((ext_vector_type(4))) float f32x4;
typedef __attribute__((ext_vector_type(8))) short s16x8;

#define MFMA16(a, b, c) __builtin_amdgcn_mfma_f32_16x16x32_bf16((a), (b), (c), 0, 0, 0)

__device__ __forceinline__ float hsig(float x) {
    return fminf(fmaxf(0.2f * x + 0.5f, 0.0f), 1.0f);
}

__device__ __forceinline__ unsigned short bf16rne(float v) {
    unsigned u = __float_as_uint(v);
    u += 0x7FFFu + ((u >> 16) & 1u);
    return (unsigned short)(u >> 16);
}
__device__ __forceinline__ void split2(float v, unsigned short& h, unsigned short& l) {
    h = bf16rne(v);
    float hv = __uint_as_float((unsigned)h << 16);
    l = bf16rne(v - hv);
}

// ---- weight prep: reorder to MFMA B-fragment order (unchanged layout) ----
// Bw layout: [ks][ hi: nfrag(16) x lane(64) x 8 | lo: same ]  (16384 ushorts per ks)
template<int KHW, int CX, int NS>
__global__ __launch_bounds__(256)
void prep_w(const float* __restrict__ Kw, const float* __restrict__ Rw,
            unsigned short* __restrict__ Bw)
{
    int gid = blockIdx.x * 256 + threadIdx.x;
    if (gid >= NS * 1024) return;
    int lane  = gid & 63;
    int nfrag = (gid >> 6) & 15;
    int ks    = gid >> 10;
    int n  = nfrag * 16 + (lane & 15);
    int kl = (lane >> 4) * 8;
    constexpr int KX = KHW * CX;
    s16x8 vh, vl;
#pragma unroll
    for (int j = 0; j < 8; ++j) {
        int kg = ks * 32 + kl + j;
        float w = (kg < KX) ? Kw[(long)kg * 256 + n]
                            : Rw[(long)(kg - KX) * 256 + n];
        unsigned short h, l;
        split2(w, h, l);
        vh[j] = (short)h;
        vl[j] = (short)l;
    }
    unsigned short* o = Bw + (long)ks * 16384 + nfrag * 512 + lane * 8;
    *(s16x8*)o = vh;
    *(s16x8*)(o + 8192) = vl;
}

// ---- stage zero-padded tile as bf16 hi/lo planes, chunk-major [c/8][pixel][8]
//      with +8-ushort per-chunk pad (CST) to break bank alignment ----
template<int C, int TS, int PAD, int CST>
__device__ __forceinline__ void stage_split(const float* __restrict__ gp,
                                            unsigned short* __restrict__ hi_,
                                            unsigned short* __restrict__ lo_,
                                            int ty0, int tx0, int tid)
{
    constexpr int CH = C / 8;
    constexpr int NP = TS * TS;
    for (int i = tid; i < NP * CH; i += 512) {
        int ch = i % CH;
        int p  = i / CH;
        int py = p / TS, px = p % TS;
        int iy = ty0 + py - PAD, ix = tx0 + px - PAD;
        float v[8];
        if (iy >= 0 && iy < 64 && ix >= 0 && ix < 64) {
            const float* s = gp + ((long)(iy * 64 + ix)) * C + ch * 8;
            f32x4 a = *(const f32x4*)s;
            f32x4 b = *(const f32x4*)(s + 4);
#pragma unroll
            for (int j = 0; j < 4; ++j) { v[j] = a[j]; v[4 + j] = b[j]; }
        } else {
#pragma unroll
            for (int j = 0; j < 8; ++j) v[j] = 0.0f;
        }
        s16x8 vh, vl;
#pragma unroll
        for (int j = 0; j < 8; ++j) {
            unsigned short h, l;
            split2(v[j], h, l);
            vh[j] = (short)h;
            vl[j] = (short)l;
        }
        *(s16x8*)(hi_ + ch * CST + p * 8) = vh;
        *(s16x8*)(lo_ + ch * CST + p * 8) = vl;
    }
}

// ---- fused ConvLSTM step, MFMA 3-pass hi/lo ----
// M=64 pixels (8x8 tile), per-block N=128 (4 gates x 32 features; nh selects
// feature half), K = KHW*(CX+64).  2 blocks/CU (LDS 2x55KB, VGPR<=128).
template<int KW, int CX, int TS, int NS, int XS>
__global__ __launch_bounds__(512, 4)
void lstm_mfma(const float* __restrict__ xin, long xbstride,
               const float* __restrict__ hin,
               const unsigned short* __restrict__ Bg,
               const float* __restrict__ bias,
               float* __restrict__ c_buf,
               float* __restrict__ h_out,
               float* __restrict__ y_out, long ybstride)
{
    constexpr int PAD = KW / 2;
    constexpr int NP  = TS * TS;
    constexpr int CHX = CX / 8;
    constexpr int CST = NP * 8 + 8;          // padded chunk stride (ushorts)
    constexpr int XPLANE = CHX * CST;
    constexpr int HPLANE = 8 * CST;
    constexpr int STAGEU = 2 * XPLANE + 2 * HPLANE;
    constexpr int ZLU    = 64 * 132 * 2;     // 8448 f32 as ushort count
    constexpr int SMEMU  = STAGEU > ZLU ? STAGEU : ZLU;
    __shared__ __align__(16) unsigned short smem[SMEMU];

    unsigned short* sxh = smem;
    unsigned short* sxl = sxh + XPLANE;
    unsigned short* shh = sxl + XPLANE;
    unsigned short* shl = shh + HPLANE;

    const int tid  = threadIdx.x;
    const int lane = tid & 63, wid = tid >> 6;
    const int mh = wid >> 2, ns = wid & 3;
    const int nh  = blockIdx.x & 1;           // feature-half of this block
    const int tx0 = (blockIdx.x >> 1) * 8;
    const int ty0 = blockIdx.y * 8;
    const int b   = blockIdx.z;

    // B fragment base: wave ns owns gate ns, features [nh*32, nh*32+32)
    const unsigned short* bp = Bg + (ns * 4 + nh * 2) * 512 + lane * 8;

    s16x8 bh0[2], bl0[2], bh1[2], bl1[2];
#define LOADB(BH, BL, Q)                                   \
    {                                                      \
        const unsigned short* q_ = (Q);                    \
        _Pragma("unroll")                                  \
        for (int nf = 0; nf < 2; ++nf) {                   \
            BH[nf] = *(const s16x8*)(q_ + nf * 512);       \
            BL[nf] = *(const s16x8*)(q_ + 8192 + nf * 512);\
        }                                                  \
    }

    LOADB(bh0, bl0, bp);  // ks=0, overlaps with staging below

    stage_split<CX, TS, PAD, CST>(xin + (long)b * xbstride, sxh, sxl, ty0, tx0, tid);
    stage_split<64, TS, PAD, CST>(hin + (long)b * 4096 * 64, shh, shl, ty0, tx0, tid);
    __syncthreads();

    f32x4 acc[2][2];
#pragma unroll
    for (int mf = 0; mf < 2; ++mf)
#pragma unroll
        for (int nf = 0; nf < 2; ++nf)
#pragma unroll
            for (int q = 0; q < 4; ++q) acc[mf][nf][q] = 0.0f;

    // thread-const A offsets (ushort units). pixel p = mh*32 + mf*16 + (lane&15)
    const int p0  = mh * 32 + (lane & 15);
    const int av0 = (((p0 >> 3) * TS) + (p0 & 7)) * 8 + (lane >> 4) * CST;
    const int p1  = p0 + 16;
    const int av1 = (((p1 >> 3) * TS) + (p1 & 7)) * 8 + (lane >> 4) * CST;

    s16x8 A0h, A0l, A1h, A1l;     // current A fragments
    s16x8 N0h, N0l, N1h, N1l;     // next A fragments (software pipeline)
#define LOADA(D0h, D0l, D1h, D1l, KS)                                    \
    {                                                                    \
        int tap_, cb8_;                                                  \
        const unsigned short *ph_, *pl_;                                 \
        if ((KS) < XS) {                                                 \
            if (CX == 32) { tap_ = (KS); cb8_ = 0; }                     \
            else { tap_ = (KS) >> 1; cb8_ = ((KS) & 1) * 4; }            \
            ph_ = sxh; pl_ = sxl;                                        \
        } else {                                                         \
            int kk_ = (KS) - XS;                                         \
            tap_ = kk_ >> 1; cb8_ = (kk_ & 1) * 4;                       \
            ph_ = shh; pl_ = shl;                                        \
        }                                                                \
        int kh_ = tap_ / KW, kw_ = tap_ - kh_ * KW;                      \
        int so_ = cb8_ * CST + (kh_ * TS + kw_) * 8;                     \
        D0h = *(const s16x8*)(ph_ + so_ + av0);                          \
        D0l = *(const s16x8*)(pl_ + so_ + av0);                          \
        D1h = *(const s16x8*)(ph_ + so_ + av1);                          \
        D1l = *(const s16x8*)(pl_ + so_ + av1);                          \
    }

#define MM(X0h, X0l, X1h, X1l, BH, BL)                        \
    {                                                         \
        _Pragma("unroll")                                     \
        for (int nf = 0; nf < 2; ++nf) {                      \
            acc[0][nf] = MFMA16(X0h, BH[nf], acc[0][nf]);     \
            acc[1][nf] = MFMA16(X1h, BH[nf], acc[1][nf]);     \
            acc[0][nf] = MFMA16(X0l, BH[nf], acc[0][nf]);     \
            acc[1][nf] = MFMA16(X1l, BH[nf], acc[1][nf]);     \
            acc[0][nf] = MFMA16(X0h, BL[nf], acc[0][nf]);     \
            acc[1][nf] = MFMA16(X1h, BL[nf], acc[1][nf]);     \
        }                                                     \
    }

    LOADA(A0h, A0l, A1h, A1l, 0);

    const unsigned short* bq = bp;
#pragma unroll 1
    for (int ks = 0; ks < NS; ks += 2) {
        if (ks + 1 < NS) {
            LOADB(bh1, bl1, bq + 16384);
            LOADA(N0h, N0l, N1h, N1l, ks + 1);
        }
        MM(A0h, A0l, A1h, A1l, bh0, bl0);
        if (ks + 1 < NS) {
            if (ks + 2 < NS) {
                LOADB(bh0, bl0, bq + 32768);
                LOADA(A0h, A0l, A1h, A1l, ks + 2);
            }
            MM(N0h, N0l, N1h, N1l, bh1, bl1);
        }
        bq += 32768;
    }

    // ---- z exchange (single round: 64 px x 32 feat x 4 gates) + gates ----
    __syncthreads();
    float* zl = (float*)smem;  // [pl][132]: fc*4+gate, row stride 132 (pad)
#pragma unroll
    for (int mf = 0; mf < 2; ++mf)
#pragma unroll
        for (int nf = 0; nf < 2; ++nf)
#pragma unroll
            for (int q = 0; q < 4; ++q) {
                int pl_ = mh * 32 + mf * 16 + (lane >> 4) * 4 + q;
                int fc  = nf * 16 + (lane & 15);
                zl[pl_ * 132 + fc * 4 + ns] = acc[mf][nf][q];
            }
    __syncthreads();

    const int fl = tid & 31;
    const int f  = nh * 32 + fl;
    const int pj = tid >> 5;
    const float bi = bias[f], bfr = bias[64 + f], bg = bias[128 + f], bo = bias[192 + f];
#pragma unroll
    for (int j = 0; j < 4; ++j) {
        int pl_ = j * 16 + pj;                  // 0..63
        f32x4 z4 = *(const f32x4*)(zl + pl_ * 132 + fl * 4);
        float zi = z4[0] + bi, zf = z4[1] + bfr, zg = z4[2] + bg, zo = z4[3] + bo;
        int y = ty0 + (pl_ >> 3), x = tx0 + (pl_ & 7);
        long o = ((long)((b * 64 + y) * 64 + x)) * 64 + f;
        float cv = c_buf[o];
        float cn = hsig(zf) * cv + hsig(zi) * tanhf(zg);
        c_buf[o] = cn;
        float hn = hsig(zo) * tanhf(cn);
        h_out[o] = hn;
        y_out[(long)b * ybstride + ((long)(y * 64 + x)) * 64 + f] = fmaxf(hn, 0.0f);
    }
#undef LOADB
#undef LOADA
#undef MM
}

extern "C" void kernel_launch(void* const* d_in, const int* in_sizes, int n_in,
                              void* d_out, int out_size, void* d_ws, size_t ws_size,
                              hipStream_t stream)
{
    const float* x  = (const float*)d_in[0];
    const float* K1 = (const float*)d_in[1];
    const float* R1 = (const float*)d_in[2];
    const float* b1 = (const float*)d_in[3];
    const float* K2 = (const float*)d_in[4];
    const float* R2 = (const float*)d_in[5];
    const float* b2 = (const float*)d_in[6];
    float* out = (float*)d_out;

    const long HW   = 4096;
    const long SZ_S = HW * 64 * 4;      // 1,048,576 floats per [B,H,W,64]
    const long SZ_Y = SZ_S * 8;

    float* ws  = (float*)d_ws;
    float* y1  = ws;                    // 8,388,608 f32
    float* h_a = y1 + SZ_Y;             // 1,048,576
    float* h_b = h_a + SZ_S;
    float* c   = h_b + SZ_S;
    unsigned short* B1 = (unsigned short*)(c + SZ_S);   // 75*16384 ushorts
    unsigned short* B2 = B1 + (long)75 * 16384;         // 36*16384 ushorts

    // weight prep
    prep_w<25, 32, 75><<<300, 256, 0, stream>>>(K1, R1, B1);
    prep_w<9,  64, 36><<<144, 256, 0, stream>>>(K2, R2, B2);

    dim3 grid(16, 8, 4);                // x lsb = feature-half (pairs stay L2-local)
    dim3 blk(512);

    // ---- layer 1: 5x5, Cin=32, K=2400 (75 ksteps, 25 x-steps) ----
    hipMemsetAsync(h_a, 0, (size_t)SZ_S * sizeof(float), stream);
    hipMemsetAsync(c,   0, (size_t)SZ_S * sizeof(float), stream);
    {
        float* hp = h_a;
        float* hn = h_b;
        for (int t = 0; t < 8; ++t) {
            lstm_mfma<5, 32, 12, 75, 25><<<grid, blk, 0, stream>>>(
                x + (long)t * HW * 32, (long)8 * HW * 32,
                hp, B1, b1, c, hn,
                y1 + (long)t * HW * 64, (long)8 * HW * 64);
            float* tmp = hp; hp = hn; hn = tmp;
        }
    }

    // ---- layer 2: 3x3, Cin=64, K=1152 (36 ksteps, 18 x-steps) ----
    hipMemsetAsync(h_a, 0, (size_t)SZ_S * sizeof(float), stream);
    hipMemsetAsync(c,   0, (size_t)SZ_S * sizeof(float), stream);
    {
        float* hp = h_a;
        float* hn = h_b;
        for (int t = 0; t < 8; ++t) {
            lstm_mfma<3, 64, 10, 36, 18><<<grid, blk, 0, stream>>>(
                y1 + (long)t * HW * 64, (long)8 * HW * 64,
                hp, B2, b2, c, hn,
                out + (long)t * HW * 64, (long)8 * HW * 64);
            float* tmp = hp; hp = hn; hn = tmp;
        }
    }
}

// Round 2
// 745.898 us; speedup vs baseline: 1.0946x; 1.0946x over previous
//
#include <hip/hip_runtime.h>

typedef __attribute__((ext_vector_type(4))) float f32x4;
typedef __attribute__((ext_vector_type(8))) short s16x8;

#define MFMA16(a, b, c) __builtin_amdgcn_mfma_f32_16x16x32_bf16((a), (b), (c), 0, 0, 0)

__device__ __forceinline__ float hsig(float x) {
    return fminf(fmaxf(0.2f * x + 0.5f, 0.0f), 1.0f);
}

__device__ __forceinline__ unsigned short bf16rne(float v) {
    unsigned u = __float_as_uint(v);
    u += 0x7FFFu + ((u >> 16) & 1u);
    return (unsigned short)(u >> 16);
}
__device__ __forceinline__ void split2(float v, unsigned short& h, unsigned short& l) {
    h = bf16rne(v);
    float hv = __uint_as_float((unsigned)h << 16);
    l = bf16rne(v - hv);
}

// ---- weight prep: reorder to MFMA B-fragment order ----
// Bw layout: [ks][ hi: nfrag(16) x lane(64) x 8 | lo: same ]  (16384 ushorts per ks)
template<int KHW, int CX, int NS>
__global__ __launch_bounds__(256)
void prep_w(const float* __restrict__ Kw, const float* __restrict__ Rw,
            unsigned short* __restrict__ Bw)
{
    int gid = blockIdx.x * 256 + threadIdx.x;
    if (gid >= NS * 1024) return;
    int lane  = gid & 63;
    int nfrag = (gid >> 6) & 15;
    int ks    = gid >> 10;
    int n  = nfrag * 16 + (lane & 15);
    int kl = (lane >> 4) * 8;
    constexpr int KX = KHW * CX;
    s16x8 vh, vl;
#pragma unroll
    for (int j = 0; j < 8; ++j) {
        int kg = ks * 32 + kl + j;
        float w = (kg < KX) ? Kw[(long)kg * 256 + n]
                            : Rw[(long)(kg - KX) * 256 + n];
        unsigned short h, l;
        split2(w, h, l);
        vh[j] = (short)h;
        vl[j] = (short)l;
    }
    unsigned short* o = Bw + (long)ks * 16384 + nfrag * 512 + lane * 8;
    *(s16x8*)o = vh;
    *(s16x8*)(o + 8192) = vl;
}

// ---- stage zero-padded tile as bf16 hi/lo planes, chunk-major [c/8][pixel][8]
//      +8-ushort per-chunk pad (CST) breaks the stage-write bank alignment ----
template<int C, int TS, int PAD, int CST>
__device__ __forceinline__ void stage_split(const float* __restrict__ gp,
                                            unsigned short* __restrict__ hi_,
                                            unsigned short* __restrict__ lo_,
                                            int ty0, int tx0, int tid)
{
    constexpr int CH = C / 8;
    constexpr int NP = TS * TS;
    for (int i = tid; i < NP * CH; i += 512) {
        int ch = i % CH;
        int p  = i / CH;
        int py = p / TS, px = p % TS;
        int iy = ty0 + py - PAD, ix = tx0 + px - PAD;
        float v[8];
        if (iy >= 0 && iy < 64 && ix >= 0 && ix < 64) {
            const float* s = gp + ((long)(iy * 64 + ix)) * C + ch * 8;
            f32x4 a = *(const f32x4*)s;
            f32x4 b = *(const f32x4*)(s + 4);
#pragma unroll
            for (int j = 0; j < 4; ++j) { v[j] = a[j]; v[4 + j] = b[j]; }
        } else {
#pragma unroll
            for (int j = 0; j < 8; ++j) v[j] = 0.0f;
        }
        s16x8 vh, vl;
#pragma unroll
        for (int j = 0; j < 8; ++j) {
            unsigned short h, l;
            split2(v[j], h, l);
            vh[j] = (short)h;
            vl[j] = (short)l;
        }
        *(s16x8*)(hi_ + ch * CST + p * 8) = vh;
        *(s16x8*)(lo_ + ch * CST + p * 8) = vl;
    }
}

// ---- fused ConvLSTM step, MFMA 3-pass hi/lo ----
// M=64 pixels (8x8 tile), N=256 gate-channels, K = KHW*(CX+64).
// 3-deep B pipeline (global loads issued 2 k-steps = ~230cy ahead of use,
// covering ~200cy L2 latency). Requires NS % 3 == 0 (75, 36 both ok).
template<int KW, int CX, int TS, int NS, int XS>
__global__ __launch_bounds__(512, 2)
void lstm_mfma(const float* __restrict__ xin, long xbstride,
               const float* __restrict__ hin,
               const unsigned short* __restrict__ Bg,
               const float* __restrict__ bias,
               float* __restrict__ c_buf,
               float* __restrict__ h_out,
               float* __restrict__ y_out, long ybstride)
{
    static_assert(NS % 3 == 0 && NS >= 6, "pipeline needs NS multiple of 3");
    constexpr int PAD = KW / 2;
    constexpr int NP  = TS * TS;
    constexpr int CHX = CX / 8;
    constexpr int CST = NP * 8 + 8;          // padded chunk stride (ushorts)
    constexpr int XPLANE = CHX * CST;
    constexpr int HPLANE = 8 * CST;
    constexpr int STAGEU = 2 * XPLANE + 2 * HPLANE;
    constexpr int ZLU    = 32 * 260 * 2;     // 32x260 f32 overlay (ushort count)
    constexpr int SMEMU  = STAGEU > ZLU ? STAGEU : ZLU;
    __shared__ __align__(16) unsigned short smem[SMEMU];

    unsigned short* sxh = smem;
    unsigned short* sxl = sxh + XPLANE;
    unsigned short* shh = sxl + XPLANE;
    unsigned short* shl = shh + HPLANE;

    const int tid  = threadIdx.x;
    const int lane = tid & 63, wid = tid >> 6;
    const int mh = wid >> 2, ns = wid & 3;
    const int b   = blockIdx.z;
    const int ty0 = blockIdx.y * 8, tx0 = blockIdx.x * 8;

    // B fragment base for this wave (ushort units); per-ks stride = 16384
    const unsigned short* bp = Bg + (ns * 4) * 512 + lane * 8;

    s16x8 Bh[3][4], Bl[3][4];
#define LOADB(BI, Q)                                             \
    {                                                            \
        const unsigned short* q_ = (Q);                          \
        _Pragma("unroll")                                        \
        for (int nf = 0; nf < 4; ++nf) {                         \
            Bh[BI][nf] = *(const s16x8*)(q_ + nf * 512);         \
            Bl[BI][nf] = *(const s16x8*)(q_ + 8192 + nf * 512);  \
        }                                                        \
    }

    LOADB(0, bp);             // ks 0, overlaps with staging
    LOADB(1, bp + 16384);     // ks 1

    stage_split<CX, TS, PAD, CST>(xin + (long)b * xbstride, sxh, sxl, ty0, tx0, tid);
    stage_split<64, TS, PAD, CST>(hin + (long)b * 4096 * 64, shh, shl, ty0, tx0, tid);
    __syncthreads();

    f32x4 acc[2][4];
#pragma unroll
    for (int mf = 0; mf < 2; ++mf)
#pragma unroll
        for (int nf = 0; nf < 4; ++nf)
#pragma unroll
            for (int q = 0; q < 4; ++q) acc[mf][nf][q] = 0.0f;

    // thread-const A offsets (ushort units). pixel p = mh*32 + mf*16 + (lane&15)
    const int p0  = mh * 32 + (lane & 15);
    const int av0 = (((p0 >> 3) * TS) + (p0 & 7)) * 8 + (lane >> 4) * CST;
    const int p1  = p0 + 16;
    const int av1 = (((p1 >> 3) * TS) + (p1 & 7)) * 8 + (lane >> 4) * CST;

    s16x8 Ar[3][4];  // [buf][ a0h, a0l, a1h, a1l ]
#define LOADA(AI, KS)                                                    \
    {                                                                    \
        int ksv_ = (KS);                                                 \
        int tap_, cb8_;                                                  \
        const unsigned short *ph_, *pl_;                                 \
        if (ksv_ < XS) {                                                 \
            if (CX == 32) { tap_ = ksv_; cb8_ = 0; }                     \
            else { tap_ = ksv_ >> 1; cb8_ = (ksv_ & 1) * 4; }            \
            ph_ = sxh; pl_ = sxl;                                        \
        } else {                                                         \
            int kk_ = ksv_ - XS;                                         \
            tap_ = kk_ >> 1; cb8_ = (kk_ & 1) * 4;                       \
            ph_ = shh; pl_ = shl;                                        \
        }                                                                \
        int kh_ = tap_ / KW, kw_ = tap_ - kh_ * KW;                      \
        int so_ = cb8_ * CST + (kh_ * TS + kw_) * 8;                     \
        Ar[AI][0] = *(const s16x8*)(ph_ + so_ + av0);                    \
        Ar[AI][1] = *(const s16x8*)(pl_ + so_ + av0);                    \
        Ar[AI][2] = *(const s16x8*)(ph_ + so_ + av1);                    \
        Ar[AI][3] = *(const s16x8*)(pl_ + so_ + av1);                    \
    }

#define MM(AI, BI)                                                    \
    {                                                                 \
        _Pragma("unroll")                                             \
        for (int nf = 0; nf < 4; ++nf) {                              \
            acc[0][nf] = MFMA16(Ar[AI][0], Bh[BI][nf], acc[0][nf]);   \
            acc[1][nf] = MFMA16(Ar[AI][2], Bh[BI][nf], acc[1][nf]);   \
            acc[0][nf] = MFMA16(Ar[AI][1], Bh[BI][nf], acc[0][nf]);   \
            acc[1][nf] = MFMA16(Ar[AI][3], Bh[BI][nf], acc[1][nf]);   \
            acc[0][nf] = MFMA16(Ar[AI][0], Bl[BI][nf], acc[0][nf]);   \
            acc[1][nf] = MFMA16(Ar[AI][2], Bl[BI][nf], acc[1][nf]);   \
        }                                                             \
    }

    LOADA(0, 0);

    const unsigned short* bq = bp;
    int ks = 0;
#pragma unroll 1
    for (; ks < NS - 3; ks += 3) {
        LOADB(2, bq + 2 * 16384);   // B for ks+2 (2 steps ahead of its MM)
        LOADA(1, ks + 1);
        MM(0, 0);
        LOADB(0, bq + 3 * 16384);   // B for ks+3
        LOADA(2, ks + 2);
        MM(1, 1);
        LOADB(1, bq + 4 * 16384);   // B for ks+4
        LOADA(0, ks + 3);
        MM(2, 2);
        bq += 3 * 16384;
    }
    // tail: ks == NS-3
    LOADB(2, bq + 2 * 16384);
    LOADA(1, ks + 1);
    MM(0, 0);
    LOADA(2, ks + 2);
    MM(1, 1);
    MM(2, 2);

    // ---- z exchange (2 rounds of 32 pixels, padded row stride 260) + gates ----
    __syncthreads();
    float* zl = (float*)smem;  // 32 x 260 f32 = 33.3 KB overlay
    const int f = tid & 63;
    const float bi = bias[f], bfr = bias[64 + f], bg = bias[128 + f], bo = bias[192 + f];

    for (int r = 0; r < 2; ++r) {
        if (mh == r) {
#pragma unroll
            for (int mf = 0; mf < 2; ++mf)
#pragma unroll
                for (int nf = 0; nf < 4; ++nf)
#pragma unroll
                    for (int q = 0; q < 4; ++q) {
                        int pl_ = mf * 16 + (lane >> 4) * 4 + q;
                        int fc  = nf * 16 + (lane & 15);
                        zl[pl_ * 260 + fc * 4 + ns] = acc[mf][nf][q];
                    }
        }
        __syncthreads();
#pragma unroll
        for (int j = 0; j < 4; ++j) {
            int pl_ = (tid >> 6) + j * 8;           // 0..31
            int p   = r * 32 + pl_;
            f32x4 z4 = *(const f32x4*)(zl + pl_ * 260 + f * 4);
            float zi = z4[0] + bi, zf = z4[1] + bfr, zg = z4[2] + bg, zo = z4[3] + bo;
            int y = ty0 + (p >> 3), x = tx0 + (p & 7);
            long o = ((long)((b * 64 + y) * 64 + x)) * 64 + f;
            float cv = c_buf[o];
            float cn = hsig(zf) * cv + hsig(zi) * tanhf(zg);
            c_buf[o] = cn;
            float hn = hsig(zo) * tanhf(cn);
            h_out[o] = hn;
            y_out[(long)b * ybstride + ((long)(y * 64 + x)) * 64 + f] = fmaxf(hn, 0.0f);
        }
        __syncthreads();
    }
#undef LOADB
#undef LOADA
#undef MM
}

extern "C" void kernel_launch(void* const* d_in, const int* in_sizes, int n_in,
                              void* d_out, int out_size, void* d_ws, size_t ws_size,
                              hipStream_t stream)
{
    const float* x  = (const float*)d_in[0];
    const float* K1 = (const float*)d_in[1];
    const float* R1 = (const float*)d_in[2];
    const float* b1 = (const float*)d_in[3];
    const float* K2 = (const float*)d_in[4];
    const float* R2 = (const float*)d_in[5];
    const float* b2 = (const float*)d_in[6];
    float* out = (float*)d_out;

    const long HW   = 4096;
    const long SZ_S = HW * 64 * 4;      // 1,048,576 floats per [B,H,W,64]
    const long SZ_Y = SZ_S * 8;

    float* ws  = (float*)d_ws;
    float* y1  = ws;                    // 8,388,608 f32
    float* h_a = y1 + SZ_Y;             // 1,048,576
    float* h_b = h_a + SZ_S;
    float* c   = h_b + SZ_S;
    unsigned short* B1 = (unsigned short*)(c + SZ_S);   // 75*16384 ushorts
    unsigned short* B2 = B1 + (long)75 * 16384;         // 36*16384 ushorts

    // weight prep
    prep_w<25, 32, 75><<<300, 256, 0, stream>>>(K1, R1, B1);
    prep_w<9,  64, 36><<<144, 256, 0, stream>>>(K2, R2, B2);

    dim3 grid(8, 8, 4);
    dim3 blk(512);

    // ---- layer 1: 5x5, Cin=32, K=2400 (75 ksteps, 25 x-steps) ----
    hipMemsetAsync(h_a, 0, (size_t)SZ_S * sizeof(float), stream);
    hipMemsetAsync(c,   0, (size_t)SZ_S * sizeof(float), stream);
    {
        float* hp = h_a;
        float* hn = h_b;
        for (int t = 0; t < 8; ++t) {
            lstm_mfma<5, 32, 12, 75, 25><<<grid, blk, 0, stream>>>(
                x + (long)t * HW * 32, (long)8 * HW * 32,
                hp, B1, b1, c, hn,
                y1 + (long)t * HW * 64, (long)8 * HW * 64);
            float* tmp = hp; hp = hn; hn = tmp;
        }
    }

    // ---- layer 2: 3x3, Cin=64, K=1152 (36 ksteps, 18 x-steps) ----
    hipMemsetAsync(h_a, 0, (size_t)SZ_S * sizeof(float), stream);
    hipMemsetAsync(c,   0, (size_t)SZ_S * sizeof(float), stream);
    {
        float* hp = h_a;
        float* hn = h_b;
        for (int t = 0; t < 8; ++t) {
            lstm_mfma<3, 64, 10, 36, 18><<<grid, blk, 0, stream>>>(
                y1 + (long)t * HW * 64, (long)8 * HW * 64,
                hp, B2, b2, c, hn,
                out + (long)t * HW * 64, (long)8 * HW * 64);
            float* tmp = hp; hp = hn; hn = tmp;
        }
    }
}

// Round 3
// 662.102 us; speedup vs baseline: 1.2331x; 1.1266x over previous
//
#include <hip/hip_runtime.h>

typedef __attribute__((ext_vector_type(4))) float f32x4;
typedef __attribute__((ext_vector_type(8))) short s16x8;

#define MFMA16(a, b, c) __builtin_amdgcn_mfma_f32_16x16x32_bf16((a), (b), (c), 0, 0, 0)

__device__ __forceinline__ float hsig(float x) {
    return fminf(fmaxf(0.2f * x + 0.5f, 0.0f), 1.0f);
}

__device__ __forceinline__ unsigned short bf16rne(float v) {
    unsigned u = __float_as_uint(v);
    u += 0x7FFFu + ((u >> 16) & 1u);
    return (unsigned short)(u >> 16);
}
__device__ __forceinline__ void split2(float v, unsigned short& h, unsigned short& l) {
    h = bf16rne(v);
    float hv = __uint_as_float((unsigned)h << 16);
    l = bf16rne(v - hv);
}

// ---- weight prep: reorder to MFMA B-fragment order ----
// Bw layout: [ks][ hi: nfrag(16) x lane(64) x 8 | lo: same ]  (16384 ushorts per ks)
template<int KHW, int CX, int NS>
__global__ __launch_bounds__(256)
void prep_w(const float* __restrict__ Kw, const float* __restrict__ Rw,
            unsigned short* __restrict__ Bw)
{
    int gid = blockIdx.x * 256 + threadIdx.x;
    if (gid >= NS * 1024) return;
    int lane  = gid & 63;
    int nfrag = (gid >> 6) & 15;
    int ks    = gid >> 10;
    int n  = nfrag * 16 + (lane & 15);
    int kl = (lane >> 4) * 8;
    constexpr int KX = KHW * CX;
    s16x8 vh, vl;
#pragma unroll
    for (int j = 0; j < 8; ++j) {
        int kg = ks * 32 + kl + j;
        float w = (kg < KX) ? Kw[(long)kg * 256 + n]
                            : Rw[(long)(kg - KX) * 256 + n];
        unsigned short h, l;
        split2(w, h, l);
        vh[j] = (short)h;
        vl[j] = (short)l;
    }
    unsigned short* o = Bw + (long)ks * 16384 + nfrag * 512 + lane * 8;
    *(s16x8*)o = vh;
    *(s16x8*)(o + 8192) = vl;
}

// ---- stage zero-padded tile as bf16 hi/lo planes, chunk-major [c/8][pixel][8] ----
template<int C, int TS, int PAD, int CST>
__device__ __forceinline__ void stage_split(const float* __restrict__ gp,
                                            unsigned short* __restrict__ hi_,
                                            unsigned short* __restrict__ lo_,
                                            int ty0, int tx0, int tid)
{
    constexpr int CH = C / 8;
    constexpr int NP = TS * TS;
    for (int i = tid; i < NP * CH; i += 512) {
        int ch = i % CH;
        int p  = i / CH;
        int py = p / TS, px = p % TS;
        int iy = ty0 + py - PAD, ix = tx0 + px - PAD;
        float v[8];
        if (iy >= 0 && iy < 64 && ix >= 0 && ix < 64) {
            const float* s = gp + ((long)(iy * 64 + ix)) * C + ch * 8;
            f32x4 a = *(const f32x4*)s;
            f32x4 b = *(const f32x4*)(s + 4);
#pragma unroll
            for (int j = 0; j < 4; ++j) { v[j] = a[j]; v[4 + j] = b[j]; }
        } else {
#pragma unroll
            for (int j = 0; j < 8; ++j) v[j] = 0.0f;
        }
        s16x8 vh, vl;
#pragma unroll
        for (int j = 0; j < 8; ++j) {
            unsigned short h, l;
            split2(v[j], h, l);
            vh[j] = (short)h;
            vl[j] = (short)l;
        }
        *(s16x8*)(hi_ + ch * CST + p * 8) = vh;
        *(s16x8*)(lo_ + ch * CST + p * 8) = vl;
    }
}

// ---- fused ConvLSTM step, MFMA 3-pass hi/lo ----
// M=64 pixels (8x8 tile), N=256 gate-channels, K = KHW*(CX+64).
// Wave remap vs r0-r2: each wave owns ALL 64 pixels (4 M-frags) x 32 columns
// (2 N-frags) -> no duplicated B reads within a block; per-block B traffic
// per k-step = 32 KB (was 64 KB) -> L2 B stream drops below the MFMA floor.
template<int KW, int CX, int TS, int NS, int XS>
__global__ __launch_bounds__(512, 2)
void lstm_mfma(const float* __restrict__ xin, long xbstride,
               const float* __restrict__ hin,
               const unsigned short* __restrict__ Bg,
               const float* __restrict__ bias,
               float* __restrict__ c_buf,
               float* __restrict__ h_out,
               float* __restrict__ y_out, long ybstride)
{
    constexpr int PAD = KW / 2;
    constexpr int NP  = TS * TS;
    constexpr int CHX = CX / 8;
    constexpr int CST = NP * 8;              // chunk stride (ushorts), r0 layout
    constexpr int XPLANE = CHX * CST;
    constexpr int HPLANE = 8 * CST;
    constexpr int STAGEU = 2 * XPLANE + 2 * HPLANE;
    constexpr int ZLU    = 32 * 260 * 2;     // 32x260 f32 overlay (ushort count)
    constexpr int SMEMU  = STAGEU > ZLU ? STAGEU : ZLU;
    __shared__ __align__(16) unsigned short smem[SMEMU];

    unsigned short* sxh = smem;
    unsigned short* sxl = sxh + XPLANE;
    unsigned short* shh = sxl + XPLANE;
    unsigned short* shl = shh + HPLANE;

    const int tid  = threadIdx.x;
    const int lane = tid & 63, wid = tid >> 6;
    const int b   = blockIdx.z;
    const int ty0 = blockIdx.y * 8, tx0 = blockIdx.x * 8;

    // B fragment base: wave w owns nfrags {2w, 2w+1} = columns [32w, 32w+32)
    const unsigned short* bp = Bg + (2 * wid) * 512 + lane * 8;

    s16x8 Bh[2][2], Bl[2][2];
#define LOADB(BI, Q)                                             \
    {                                                            \
        const unsigned short* q_ = (Q);                          \
        Bh[BI][0] = *(const s16x8*)(q_);                         \
        Bh[BI][1] = *(const s16x8*)(q_ + 512);                   \
        Bl[BI][0] = *(const s16x8*)(q_ + 8192);                  \
        Bl[BI][1] = *(const s16x8*)(q_ + 8192 + 512);            \
    }

    LOADB(0, bp);             // ks 0, overlaps with staging

    stage_split<CX, TS, PAD, CST>(xin + (long)b * xbstride, sxh, sxl, ty0, tx0, tid);
    stage_split<64, TS, PAD, CST>(hin + (long)b * 4096 * 64, shh, shl, ty0, tx0, tid);
    __syncthreads();

    f32x4 acc[4][2];
#pragma unroll
    for (int mf = 0; mf < 4; ++mf)
#pragma unroll
        for (int nf = 0; nf < 2; ++nf)
#pragma unroll
            for (int q = 0; q < 4; ++q) acc[mf][nf][q] = 0.0f;

    // thread-const A offsets (ushort units). pixel p = mf*16 + (lane&15)
    const int pb  = lane & 15;
    const int kq  = (lane >> 4) * CST;
    const int av0 = (((pb      >> 3) * TS) + (pb      & 7)) * 8 + kq;
    const int av1 = ((((pb+16) >> 3) * TS) + ((pb+16) & 7)) * 8 + kq;
    const int av2 = ((((pb+32) >> 3) * TS) + ((pb+32) & 7)) * 8 + kq;
    const int av3 = ((((pb+48) >> 3) * TS) + ((pb+48) & 7)) * 8 + kq;

    s16x8 Ar[2][8];  // [buf][ mf0..3 hi | mf0..3 lo ]
#define LOADA(AI, KS)                                                    \
    {                                                                    \
        int ksv_ = (KS);                                                 \
        int tap_, cb8_;                                                  \
        const unsigned short *ph_, *pl_;                                 \
        if (ksv_ < XS) {                                                 \
            if (CX == 32) { tap_ = ksv_; cb8_ = 0; }                     \
            else { tap_ = ksv_ >> 1; cb8_ = (ksv_ & 1) * 4; }            \
            ph_ = sxh; pl_ = sxl;                                        \
        } else {                                                         \
            int kk_ = ksv_ - XS;                                         \
            tap_ = kk_ >> 1; cb8_ = (kk_ & 1) * 4;                       \
            ph_ = shh; pl_ = shl;                                        \
        }                                                                \
        int kh_ = tap_ / KW, kw_ = tap_ - kh_ * KW;                      \
        int so_ = cb8_ * CST + (kh_ * TS + kw_) * 8;                     \
        Ar[AI][0] = *(const s16x8*)(ph_ + so_ + av0);                    \
        Ar[AI][1] = *(const s16x8*)(ph_ + so_ + av1);                    \
        Ar[AI][2] = *(const s16x8*)(ph_ + so_ + av2);                    \
        Ar[AI][3] = *(const s16x8*)(ph_ + so_ + av3);                    \
        Ar[AI][4] = *(const s16x8*)(pl_ + so_ + av0);                    \
        Ar[AI][5] = *(const s16x8*)(pl_ + so_ + av1);                    \
        Ar[AI][6] = *(const s16x8*)(pl_ + so_ + av2);                    \
        Ar[AI][7] = *(const s16x8*)(pl_ + so_ + av3);                    \
    }

    // 3 passes: ah*bh, al*bh, ah*bl ; 8 independent acc chains, depth 3
#define MM(AI, BI)                                                       \
    {                                                                    \
        _Pragma("unroll")                                                \
        for (int mf = 0; mf < 4; ++mf) {                                 \
            acc[mf][0] = MFMA16(Ar[AI][mf], Bh[BI][0], acc[mf][0]);      \
            acc[mf][1] = MFMA16(Ar[AI][mf], Bh[BI][1], acc[mf][1]);     \
        }                                                                \
        _Pragma("unroll")                                                \
        for (int mf = 0; mf < 4; ++mf) {                                 \
            acc[mf][0] = MFMA16(Ar[AI][4+mf], Bh[BI][0], acc[mf][0]);    \
            acc[mf][1] = MFMA16(Ar[AI][4+mf], Bh[BI][1], acc[mf][1]);   \
        }                                                                \
        _Pragma("unroll")                                                \
        for (int mf = 0; mf < 4; ++mf) {                                 \
            acc[mf][0] = MFMA16(Ar[AI][mf], Bl[BI][0], acc[mf][0]);      \
            acc[mf][1] = MFMA16(Ar[AI][mf], Bl[BI][1], acc[mf][1]);     \
        }                                                                \
    }

    LOADA(0, 0);

    const unsigned short* bq = bp;
    int ks = 0;
#pragma unroll 1
    for (; ks + 1 < NS; ks += 2, bq += 32768) {
        LOADB(1, bq + 16384);
        LOADA(1, ks + 1);
        MM(0, 0);
        if (ks + 2 < NS) {
            LOADB(0, bq + 32768);
            LOADA(0, ks + 2);
        }
        MM(1, 1);
    }
    if (ks < NS) MM(0, 0);   // odd-NS tail (buf0 holds ks)

    // ---- z exchange (2 rounds of 32 pixels, row stride 260) + gates ----
    __syncthreads();
    float* zl = (float*)smem;  // 32 x 260 f32 = 33.3 KB overlay
    const int f = tid & 63;
    const float bi = bias[f], bfr = bias[64 + f], bg = bias[128 + f], bo = bias[192 + f];

#define ZROUND(RR)                                                            \
    {                                                                         \
        _Pragma("unroll")                                                     \
        for (int mi = 0; mi < 2; ++mi)                                        \
        {                                                                     \
            _Pragma("unroll")                                                 \
            for (int nf = 0; nf < 2; ++nf)                                    \
            {                                                                 \
                _Pragma("unroll")                                             \
                for (int q = 0; q < 4; ++q) {                                 \
                    int pl_ = mi * 16 + (lane >> 4) * 4 + q;                  \
                    int c   = wid * 32 + nf * 16 + (lane & 15);               \
                    zl[pl_ * 260 + (c & 63) * 4 + (c >> 6)] =                 \
                        acc[2 * (RR) + mi][nf][q];                            \
                }                                                             \
            }                                                                 \
        }                                                                     \
        __syncthreads();                                                      \
        _Pragma("unroll")                                                     \
        for (int j = 0; j < 4; ++j) {                                         \
            int pl_ = (tid >> 6) + j * 8;                                     \
            int p   = (RR) * 32 + pl_;                                        \
            f32x4 z4 = *(const f32x4*)(zl + pl_ * 260 + f * 4);               \
            float zi = z4[0] + bi, zf = z4[1] + bfr;                          \
            float zg = z4[2] + bg, zo = z4[3] + bo;                           \
            int y = ty0 + (p >> 3), x = tx0 + (p & 7);                        \
            long o = ((long)((b * 64 + y) * 64 + x)) * 64 + f;                \
            float cv = c_buf[o];                                              \
            float cn = hsig(zf) * cv + hsig(zi) * tanhf(zg);                  \
            c_buf[o] = cn;                                                    \
            float hn = hsig(zo) * tanhf(cn);                                  \
            h_out[o] = hn;                                                    \
            y_out[(long)b * ybstride + ((long)(y * 64 + x)) * 64 + f] =       \
                fmaxf(hn, 0.0f);                                              \
        }                                                                     \
        __syncthreads();                                                      \
    }

    ZROUND(0)
    ZROUND(1)

#undef LOADB
#undef LOADA
#undef MM
#undef ZROUND
}

extern "C" void kernel_launch(void* const* d_in, const int* in_sizes, int n_in,
                              void* d_out, int out_size, void* d_ws, size_t ws_size,
                              hipStream_t stream)
{
    const float* x  = (const float*)d_in[0];
    const float* K1 = (const float*)d_in[1];
    const float* R1 = (const float*)d_in[2];
    const float* b1 = (const float*)d_in[3];
    const float* K2 = (const float*)d_in[4];
    const float* R2 = (const float*)d_in[5];
    const float* b2 = (const float*)d_in[6];
    float* out = (float*)d_out;

    const long HW   = 4096;
    const long SZ_S = HW * 64 * 4;      // 1,048,576 floats per [B,H,W,64]
    const long SZ_Y = SZ_S * 8;

    float* ws  = (float*)d_ws;
    float* y1  = ws;                    // 8,388,608 f32
    float* h_a = y1 + SZ_Y;             // 1,048,576
    float* h_b = h_a + SZ_S;
    float* c   = h_b + SZ_S;
    unsigned short* B1 = (unsigned short*)(c + SZ_S);   // 75*16384 ushorts
    unsigned short* B2 = B1 + (long)75 * 16384;         // 36*16384 ushorts

    // weight prep
    prep_w<25, 32, 75><<<300, 256, 0, stream>>>(K1, R1, B1);
    prep_w<9,  64, 36><<<144, 256, 0, stream>>>(K2, R2, B2);

    dim3 grid(8, 8, 4);
    dim3 blk(512);

    // ---- layer 1: 5x5, Cin=32, K=2400 (75 ksteps, 25 x-steps) ----
    hipMemsetAsync(h_a, 0, (size_t)SZ_S * sizeof(float), stream);
    hipMemsetAsync(c,   0, (size_t)SZ_S * sizeof(float), stream);
    {
        float* hp = h_a;
        float* hn = h_b;
        for (int t = 0; t < 8; ++t) {
            lstm_mfma<5, 32, 12, 75, 25><<<grid, blk, 0, stream>>>(
                x + (long)t * HW * 32, (long)8 * HW * 32,
                hp, B1, b1, c, hn,
                y1 + (long)t * HW * 64, (long)8 * HW * 64);
            float* tmp = hp; hp = hn; hn = tmp;
        }
    }

    // ---- layer 2: 3x3, Cin=64, K=1152 (36 ksteps, 18 x-steps) ----
    hipMemsetAsync(h_a, 0, (size_t)SZ_S * sizeof(float), stream);
    hipMemsetAsync(c,   0, (size_t)SZ_S * sizeof(float), stream);
    {
        float* hp = h_a;
        float* hn = h_b;
        for (int t = 0; t < 8; ++t) {
            lstm_mfma<3, 64, 10, 36, 18><<<grid, blk, 0, stream>>>(
                y1 + (long)t * HW * 64, (long)8 * HW * 64,
                hp, B2, b2, c, hn,
                out + (long)t * HW * 64, (long)8 * HW * 64);
            float* tmp = hp; hp = hn; hn = tmp;
        }
    }
}

// Round 4
// 657.054 us; speedup vs baseline: 1.2426x; 1.0077x over previous
//
#include <hip/hip_runtime.h>

typedef __attribute__((ext_vector_type(4))) float f32x4;
typedef __attribute__((ext_vector_type(8))) short s16x8;

#define MFMA16(a, b, c) __builtin_amdgcn_mfma_f32_16x16x32_bf16((a), (b), (c), 0, 0, 0)

__device__ __forceinline__ float hsig(float x) {
    return fminf(fmaxf(0.2f * x + 0.5f, 0.0f), 1.0f);
}

__device__ __forceinline__ unsigned short bf16rne(float v) {
    unsigned u = __float_as_uint(v);
    u += 0x7FFFu + ((u >> 16) & 1u);
    return (unsigned short)(u >> 16);
}
__device__ __forceinline__ void split2(float v, unsigned short& h, unsigned short& l) {
    h = bf16rne(v);
    float hv = __uint_as_float((unsigned)h << 16);
    l = bf16rne(v - hv);
}

// ---- weight prep: reorder to MFMA B-fragment order ----
// Bw layout: [ks][ hi: nfrag(16) x lane(64) x 8 | lo: same ]  (16384 ushorts per ks)
template<int KHW, int CX, int NS>
__global__ __launch_bounds__(256)
void prep_w(const float* __restrict__ Kw, const float* __restrict__ Rw,
            unsigned short* __restrict__ Bw)
{
    int gid = blockIdx.x * 256 + threadIdx.x;
    if (gid >= NS * 1024) return;
    int lane  = gid & 63;
    int nfrag = (gid >> 6) & 15;
    int ks    = gid >> 10;
    int n  = nfrag * 16 + (lane & 15);
    int kl = (lane >> 4) * 8;
    constexpr int KX = KHW * CX;
    s16x8 vh, vl;
#pragma unroll
    for (int j = 0; j < 8; ++j) {
        int kg = ks * 32 + kl + j;
        float w = (kg < KX) ? Kw[(long)kg * 256 + n]
                            : Rw[(long)(kg - KX) * 256 + n];
        unsigned short h, l;
        split2(w, h, l);
        vh[j] = (short)h;
        vl[j] = (short)l;
    }
    unsigned short* o = Bw + (long)ks * 16384 + nfrag * 512 + lane * 8;
    *(s16x8*)o = vh;
    *(s16x8*)(o + 8192) = vl;
}

// ---- stage zero-padded tile as bf16 hi/lo planes, chunk-major [c/8][pixel][8] ----
template<int C, int TS, int PAD, int CST>
__device__ __forceinline__ void stage_split(const float* __restrict__ gp,
                                            unsigned short* __restrict__ hi_,
                                            unsigned short* __restrict__ lo_,
                                            int ty0, int tx0, int tid)
{
    constexpr int CH = C / 8;
    constexpr int NP = TS * TS;
    for (int i = tid; i < NP * CH; i += 512) {
        int ch = i % CH;
        int p  = i / CH;
        int py = p / TS, px = p % TS;
        int iy = ty0 + py - PAD, ix = tx0 + px - PAD;
        float v[8];
        if (iy >= 0 && iy < 64 && ix >= 0 && ix < 64) {
            const float* s = gp + ((long)(iy * 64 + ix)) * C + ch * 8;
            f32x4 a = *(const f32x4*)s;
            f32x4 b = *(const f32x4*)(s + 4);
#pragma unroll
            for (int j = 0; j < 4; ++j) { v[j] = a[j]; v[4 + j] = b[j]; }
        } else {
#pragma unroll
            for (int j = 0; j < 8; ++j) v[j] = 0.0f;
        }
        s16x8 vh, vl;
#pragma unroll
        for (int j = 0; j < 8; ++j) {
            unsigned short h, l;
            split2(v[j], h, l);
            vh[j] = (short)h;
            vl[j] = (short)l;
        }
        *(s16x8*)(hi_ + ch * CST + p * 8) = vh;
        *(s16x8*)(lo_ + ch * CST + p * 8) = vl;
    }
}

// ---- fused ConvLSTM step, MFMA 3-pass hi/lo ----
// M=64 pixels (8x8 tile), N=256 gate-channels, K = KHW*(CX+64).
// Wave map (r4): 8 waves = 2 K-groups x 4 N-quarters. Each wave owns all 64
// pixels x 64 columns x half the k-steps (partial sums). A-LDS traffic per
// k-step = 4 waves x 8KB = 32KB (halved vs r3); B-L2 has zero duplication.
// K-group partials are summed through the z-exchange LDS overlay.
template<int KW, int CX, int TS, int NS, int XS>
__global__ __launch_bounds__(512, 2)
void lstm_mfma(const float* __restrict__ xin, long xbstride,
               const float* __restrict__ hin,
               const unsigned short* __restrict__ Bg,
               const float* __restrict__ bias,
               float* __restrict__ c_buf,
               float* __restrict__ h_out,
               float* __restrict__ y_out, long ybstride)
{
    constexpr int PAD = KW / 2;
    constexpr int NP  = TS * TS;
    constexpr int CHX = CX / 8;
    constexpr int CST = NP * 8;              // chunk stride (ushorts)
    constexpr int XPLANE = CHX * CST;
    constexpr int HPLANE = 8 * CST;
    constexpr int STAGEU = 2 * XPLANE + 2 * HPLANE;
    constexpr int ZST = 260;                 // z row stride (f32)
    constexpr int ZPL = 32 * ZST;            // per-K-group plane (f32)
    constexpr int ZLU = 2 * ZPL * 2;         // ushort count
    constexpr int SMEMU = STAGEU > ZLU ? STAGEU : ZLU;
    constexpr int SPLIT = (NS + 1) / 2;      // k-group boundary
    __shared__ __align__(16) unsigned short smem[SMEMU];

    unsigned short* sxh = smem;
    unsigned short* sxl = sxh + XPLANE;
    unsigned short* shh = sxl + XPLANE;
    unsigned short* shl = shh + HPLANE;

    const int tid  = threadIdx.x;
    const int lane = tid & 63, wid = tid >> 6;
    const int nq = wid & 3;                  // N-quarter: columns [64nq, 64nq+64)
    const int kg = wid >> 2;                 // K-group
    const int b   = blockIdx.z;
    const int ty0 = blockIdx.y * 8, tx0 = blockIdx.x * 8;

    const int ks0 = kg ? SPLIT : 0;
    const int ks1 = kg ? NS : SPLIT;

    // B fragment base: wave owns nfrags [4nq, 4nq+4), starting at k-step ks0
    const unsigned short* bp = Bg + (long)ks0 * 16384 + (nq * 4) * 512 + lane * 8;

    s16x8 Bh[2][4], Bl[2][4];
#define LOADB(BI, Q)                                             \
    {                                                            \
        const unsigned short* q_ = (Q);                          \
        _Pragma("unroll")                                        \
        for (int nf = 0; nf < 4; ++nf) {                         \
            Bh[BI][nf] = *(const s16x8*)(q_ + nf * 512);         \
            Bl[BI][nf] = *(const s16x8*)(q_ + 8192 + nf * 512);  \
        }                                                        \
    }

    LOADB(0, bp);             // first k-step, overlaps with staging

    stage_split<CX, TS, PAD, CST>(xin + (long)b * xbstride, sxh, sxl, ty0, tx0, tid);
    stage_split<64, TS, PAD, CST>(hin + (long)b * 4096 * 64, shh, shl, ty0, tx0, tid);
    __syncthreads();

    f32x4 acc[4][4];
#pragma unroll
    for (int mf = 0; mf < 4; ++mf)
#pragma unroll
        for (int nf = 0; nf < 4; ++nf)
#pragma unroll
            for (int q = 0; q < 4; ++q) acc[mf][nf][q] = 0.0f;

    // thread-const A offsets (ushort units). pixel p = mf*16 + (lane&15)
    const int pb  = lane & 15;
    const int kq  = (lane >> 4) * CST;
    const int av0 = (((pb      >> 3) * TS) + (pb      & 7)) * 8 + kq;
    const int av1 = ((((pb+16) >> 3) * TS) + ((pb+16) & 7)) * 8 + kq;
    const int av2 = ((((pb+32) >> 3) * TS) + ((pb+32) & 7)) * 8 + kq;
    const int av3 = ((((pb+48) >> 3) * TS) + ((pb+48) & 7)) * 8 + kq;

    s16x8 Ar[2][8];  // [buf][ mf0..3 hi | mf0..3 lo ]
#define LOADA(AI, KS)                                                    \
    {                                                                    \
        int ksv_ = (KS);                                                 \
        int tap_, cb8_;                                                  \
        const unsigned short *ph_, *pl_;                                 \
        if (ksv_ < XS) {                                                 \
            if (CX == 32) { tap_ = ksv_; cb8_ = 0; }                     \
            else { tap_ = ksv_ >> 1; cb8_ = (ksv_ & 1) * 4; }            \
            ph_ = sxh; pl_ = sxl;                                        \
        } else {                                                         \
            int kk_ = ksv_ - XS;                                         \
            tap_ = kk_ >> 1; cb8_ = (kk_ & 1) * 4;                       \
            ph_ = shh; pl_ = shl;                                        \
        }                                                                \
        int kh_ = tap_ / KW, kw_ = tap_ - kh_ * KW;                      \
        int so_ = cb8_ * CST + (kh_ * TS + kw_) * 8;                     \
        Ar[AI][0] = *(const s16x8*)(ph_ + so_ + av0);                    \
        Ar[AI][1] = *(const s16x8*)(ph_ + so_ + av1);                    \
        Ar[AI][2] = *(const s16x8*)(ph_ + so_ + av2);                    \
        Ar[AI][3] = *(const s16x8*)(ph_ + so_ + av3);                    \
        Ar[AI][4] = *(const s16x8*)(pl_ + so_ + av0);                    \
        Ar[AI][5] = *(const s16x8*)(pl_ + so_ + av1);                    \
        Ar[AI][6] = *(const s16x8*)(pl_ + so_ + av2);                    \
        Ar[AI][7] = *(const s16x8*)(pl_ + so_ + av3);                    \
    }

    // 3 passes: ah*bh, al*bh, ah*bl ; 16 independent acc chains
#define MM(AI, BI)                                                        \
    {                                                                     \
        _Pragma("unroll")                                                 \
        for (int nf = 0; nf < 4; ++nf)                                    \
        {                                                                 \
            _Pragma("unroll")                                             \
            for (int mf = 0; mf < 4; ++mf)                                \
                acc[mf][nf] = MFMA16(Ar[AI][mf], Bh[BI][nf], acc[mf][nf]);\
        }                                                                 \
        _Pragma("unroll")                                                 \
        for (int nf = 0; nf < 4; ++nf)                                    \
        {                                                                 \
            _Pragma("unroll")                                             \
            for (int mf = 0; mf < 4; ++mf)                                \
                acc[mf][nf] = MFMA16(Ar[AI][4+mf], Bh[BI][nf], acc[mf][nf]);\
        }                                                                 \
        _Pragma("unroll")                                                 \
        for (int nf = 0; nf < 4; ++nf)                                    \
        {                                                                 \
            _Pragma("unroll")                                             \
            for (int mf = 0; mf < 4; ++mf)                                \
                acc[mf][nf] = MFMA16(Ar[AI][mf], Bl[BI][nf], acc[mf][nf]);\
        }                                                                 \
    }

    LOADA(0, ks0);

    const unsigned short* bq = bp;
    int ks = ks0;
#pragma unroll 1
    for (; ks + 1 < ks1; ks += 2, bq += 32768) {
        LOADB(1, bq + 16384);
        LOADA(1, ks + 1);
        MM(0, 0);
        if (ks + 2 < ks1) {
            LOADB(0, bq + 32768);
            LOADA(0, ks + 2);
        }
        MM(1, 1);
    }
    if (ks < ks1) MM(0, 0);   // odd-count tail (buf0 holds ks)

    // ---- z exchange: per-K-group planes, 2 rounds of 32 pixels ----
    __syncthreads();
    float* zl = (float*)smem;  // [kg][32][ZST] f32 = 66.5 KB overlay
    const int f = tid & 63;
    const float bi = bias[f], bfr = bias[64 + f], bg = bias[128 + f], bo = bias[192 + f];

#define ZROUND(RR)                                                            \
    {                                                                         \
        _Pragma("unroll")                                                     \
        for (int mi = 0; mi < 2; ++mi)                                        \
        {                                                                     \
            _Pragma("unroll")                                                 \
            for (int nf = 0; nf < 4; ++nf)                                    \
            {                                                                 \
                _Pragma("unroll")                                             \
                for (int q = 0; q < 4; ++q) {                                 \
                    int pl_ = mi * 16 + (lane >> 4) * 4 + q;                  \
                    int c   = nq * 64 + nf * 16 + (lane & 15);                \
                    zl[kg * ZPL + pl_ * ZST + (c & 63) * 4 + (c >> 6)] =      \
                        acc[2 * (RR) + mi][nf][q];                            \
                }                                                             \
            }                                                                 \
        }                                                                     \
        __syncthreads();                                                      \
        _Pragma("unroll")                                                     \
        for (int j = 0; j < 4; ++j) {                                         \
            int pl_ = (tid >> 6) + j * 8;                                     \
            int p   = (RR) * 32 + pl_;                                        \
            f32x4 za = *(const f32x4*)(zl + pl_ * ZST + f * 4);               \
            f32x4 zb = *(const f32x4*)(zl + ZPL + pl_ * ZST + f * 4);         \
            float zi = za[0] + zb[0] + bi, zf = za[1] + zb[1] + bfr;          \
            float zg = za[2] + zb[2] + bg, zo = za[3] + zb[3] + bo;           \
            int y = ty0 + (p >> 3), x = tx0 + (p & 7);                        \
            long o = ((long)((b * 64 + y) * 64 + x)) * 64 + f;                \
            float cv = c_buf[o];                                              \
            float cn = hsig(zf) * cv + hsig(zi) * tanhf(zg);                  \
            c_buf[o] = cn;                                                    \
            float hn = hsig(zo) * tanhf(cn);                                  \
            h_out[o] = hn;                                                    \
            y_out[(long)b * ybstride + ((long)(y * 64 + x)) * 64 + f] =       \
                fmaxf(hn, 0.0f);                                              \
        }                                                                     \
        __syncthreads();                                                      \
    }

    ZROUND(0)
    ZROUND(1)

#undef LOADB
#undef LOADA
#undef MM
#undef ZROUND
}

extern "C" void kernel_launch(void* const* d_in, const int* in_sizes, int n_in,
                              void* d_out, int out_size, void* d_ws, size_t ws_size,
                              hipStream_t stream)
{
    const float* x  = (const float*)d_in[0];
    const float* K1 = (const float*)d_in[1];
    const float* R1 = (const float*)d_in[2];
    const float* b1 = (const float*)d_in[3];
    const float* K2 = (const float*)d_in[4];
    const float* R2 = (const float*)d_in[5];
    const float* b2 = (const float*)d_in[6];
    float* out = (float*)d_out;

    const long HW   = 4096;
    const long SZ_S = HW * 64 * 4;      // 1,048,576 floats per [B,H,W,64]
    const long SZ_Y = SZ_S * 8;

    float* ws  = (float*)d_ws;
    float* y1  = ws;                    // 8,388,608 f32
    float* h_a = y1 + SZ_Y;             // 1,048,576
    float* h_b = h_a + SZ_S;
    float* c   = h_b + SZ_S;
    unsigned short* B1 = (unsigned short*)(c + SZ_S);   // 75*16384 ushorts
    unsigned short* B2 = B1 + (long)75 * 16384;         // 36*16384 ushorts

    // weight prep
    prep_w<25, 32, 75><<<300, 256, 0, stream>>>(K1, R1, B1);
    prep_w<9,  64, 36><<<144, 256, 0, stream>>>(K2, R2, B2);

    dim3 grid(8, 8, 4);
    dim3 blk(512);

    // ---- layer 1: 5x5, Cin=32, K=2400 (75 ksteps, 25 x-steps) ----
    hipMemsetAsync(h_a, 0, (size_t)SZ_S * sizeof(float), stream);
    hipMemsetAsync(c,   0, (size_t)SZ_S * sizeof(float), stream);
    {
        float* hp = h_a;
        float* hn = h_b;
        for (int t = 0; t < 8; ++t) {
            lstm_mfma<5, 32, 12, 75, 25><<<grid, blk, 0, stream>>>(
                x + (long)t * HW * 32, (long)8 * HW * 32,
                hp, B1, b1, c, hn,
                y1 + (long)t * HW * 64, (long)8 * HW * 64);
            float* tmp = hp; hp = hn; hn = tmp;
        }
    }

    // ---- layer 2: 3x3, Cin=64, K=1152 (36 ksteps, 18 x-steps) ----
    hipMemsetAsync(h_a, 0, (size_t)SZ_S * sizeof(float), stream);
    hipMemsetAsync(c,   0, (size_t)SZ_S * sizeof(float), stream);
    {
        float* hp = h_a;
        float* hn = h_b;
        for (int t = 0; t < 8; ++t) {
            lstm_mfma<3, 64, 10, 36, 18><<<grid, blk, 0, stream>>>(
                y1 + (long)t * HW * 64, (long)8 * HW * 64,
                hp, B2, b2, c, hn,
                out + (long)t * HW * 64, (long)8 * HW * 64);
            float* tmp = hp; hp = hn; hn = tmp;
        }
    }
}